// Round 2
// baseline (192.016 us; speedup 1.0000x reference)
//
#include <hip/hip_runtime.h>
#include <hip/hip_bf16.h>
#include <math.h>

#define EN 8192
#define EL 8192
#define D  256
#define NG 64
#define INF_BITS 0x7f800000u

typedef __attribute__((ext_vector_type(8))) short  bf16x8;
typedef __attribute__((ext_vector_type(4))) float  f32x4;

__device__ __forceinline__ unsigned short f2bf(float f) {
    unsigned u = __float_as_uint(f);
    unsigned r = (u + 0x7fffu + ((u >> 16) & 1u)) >> 16;   // RNE
    return (unsigned short)r;
}

// ---------------- kernel 1: fused init + edge features ----------------
// blocks [0,1024): fill bufN/bufL (contiguous 4 MB) with +inf via uint4
// blocks [1024,3072): edge features for node set
// blocks [3072,5120): edge features for label set
__global__ void prep(const float* __restrict__ h,
                     const int* __restrict__ node_edge,
                     const int* __restrict__ label_edge,
                     unsigned short* __restrict__ efn, float* __restrict__ normN,
                     unsigned short* __restrict__ efl, float* __restrict__ normL,
                     unsigned* __restrict__ inf_buf)
{
    int b = blockIdx.x;
    if (b < 1024) {
        uint4 v = make_uint4(INF_BITS, INF_BITS, INF_BITS, INF_BITS);
        ((uint4*)inf_buf)[b * 256 + threadIdx.x] = v;
        return;
    }
    b -= 1024;
    const int* edges; unsigned short* ef; float* norm;
    if (b < 2048) { edges = node_edge;  ef = efn; norm = normN; }
    else          { b -= 2048; edges = label_edge; ef = efl; norm = normL; }

    int wave = threadIdx.x >> 6;
    int lane = threadIdx.x & 63;
    int e = b * 4 + wave;
    int a  = edges[e];
    int bb = edges[EN + e];          // En == El == 8192
    float4 va = ((const float4*)(h + (size_t)a  * D))[lane];
    float4 vb = ((const float4*)(h + (size_t)bb * D))[lane];
    float4 f;
    f.x = 0.5f * (va.x + vb.x);
    f.y = 0.5f * (va.y + vb.y);
    f.z = 0.5f * (va.z + vb.z);
    f.w = 0.5f * (va.w + vb.w);
    float sq = f.x*f.x + f.y*f.y + f.z*f.z + f.w*f.w;
    ushort4 pk;
    pk.x = f2bf(f.x); pk.y = f2bf(f.y); pk.z = f2bf(f.z); pk.w = f2bf(f.w);
    ((ushort4*)(ef + (size_t)e * D))[lane] = pk;
    #pragma unroll
    for (int off = 1; off < 64; off <<= 1)
        sq += __shfl_xor(sq, off, 64);
    if (lane == 0) norm[e] = sq;
}

// ---------------- kernel 2: fused GEMM + sq-distance + segmented min ----------------
// 512 threads, 8 waves; wave-tile 32 rows x 64 cols (acc[2][4]).
// R1: double-buffered LDS (32->64 KB) + prefetch-next-tile-before-compute
// (T3 "minimum 2-phase" recipe): the stage for kt+1 is issued before the
// ds_read+MFMA of kt, so global->LDS latency hides under compute on 3 of 4
// K-steps. Barriers: 8 -> 5. The single __syncthreads per iteration
// (compiler emits vmcnt(0) lgkmcnt(0) before s_barrier) orders both
// cross-iteration hazards: (a) stage writes buf[cur^1] land before next
// iter reads them; (b) this iter's ds_reads of buf[cur] complete (lgkmcnt
// drained per-wave pre-barrier) before any wave's next-iter stage
// overwrites buf[cur]. LDS XOR-swizzle -> 0 bank conflicts (verified R4 of
// prior session). Epilogue unchanged (wave-uniform fast paths; sqrt
// deferred to finalize).
__launch_bounds__(512, 4)
__global__ void dist_min(const unsigned short* __restrict__ A,   // ef_n [EN][D]
                         const unsigned short* __restrict__ B,   // ef_l [EL][D]
                         const float* __restrict__ normN,
                         const float* __restrict__ normL,
                         const int* __restrict__ node_batch,
                         const int* __restrict__ label_batch,
                         unsigned* __restrict__ bufN,  // [EN][NG] min sq-dist bits
                         unsigned* __restrict__ bufL)  // [NG][EL] min sq-dist bits
{
    __shared__ unsigned short As[2][128 * 64];
    __shared__ unsigned short Bs[2][128 * 64];

    const int tid  = threadIdx.x;
    const int lane = tid & 63;
    const int wave = tid >> 6;          // 0..7
    const int quad = lane >> 4;
    const int lc   = lane & 15;
    const int m0   = blockIdx.y * 128;
    const int n0   = blockIdx.x * 128;
    const int wr   = (wave >> 1) * 32;  // 4 row groups of 32
    const int wc   = (wave & 1) * 64;   // 2 col groups of 64

    f32x4 acc[2][4];
    #pragma unroll
    for (int i = 0; i < 2; ++i)
        #pragma unroll
        for (int j = 0; j < 4; ++j) {
            f32x4 z = {0.f, 0.f, 0.f, 0.f};
            acc[i][j] = z;
        }

    // stage tiles for K-step kt into LDS buffer `buf`; phys chunk (row, cc)
    // holds global chunk (row, cc^(row&7))
    auto stage = [&](int buf, int kt) {
        #pragma unroll
        for (int t = 0; t < 2; ++t) {
            int c = t * 512 + tid;              // chunk id, linear in tid
            int row = c >> 3, cc = c & 7;
            int scc = cc ^ (row & 7);
            const unsigned short* gp = A + (size_t)(m0 + row) * D + kt * 64 + scc * 8;
            __builtin_amdgcn_global_load_lds(
                (const __attribute__((address_space(1))) void*)gp,
                (__attribute__((address_space(3))) void*)(As[buf] + c * 8), 16, 0, 0);
        }
        #pragma unroll
        for (int t = 0; t < 2; ++t) {
            int c = t * 512 + tid;
            int row = c >> 3, cc = c & 7;
            int scc = cc ^ (row & 7);
            const unsigned short* gp = B + (size_t)(n0 + row) * D + kt * 64 + scc * 8;
            __builtin_amdgcn_global_load_lds(
                (const __attribute__((address_space(1))) void*)gp,
                (__attribute__((address_space(3))) void*)(Bs[buf] + c * 8), 16, 0, 0);
        }
    };

    stage(0, 0);
    __syncthreads();                            // drain prologue stage

    int cur = 0;
    for (int kt = 0; kt < 4; ++kt) {            // K = 256 = 4 * 64
        if (kt < 3) stage(cur ^ 1, kt + 1);     // prefetch next tile (other buf)

        #pragma unroll
        for (int kk = 0; kk < 2; ++kk) {        // two k=32 steps
            bf16x8 af[2], bfv[4];
            #pragma unroll
            for (int mi = 0; mi < 2; ++mi)
                af[mi] = *(const bf16x8*)(As[cur] + (wr + mi*16 + lc) * 64
                                             + ((kk*4 + quad) ^ (lc & 7)) * 8);
            #pragma unroll
            for (int ni = 0; ni < 4; ++ni)
                bfv[ni] = *(const bf16x8*)(Bs[cur] + (wc + ni*16 + lc) * 64
                                              + ((kk*4 + quad) ^ (lc & 7)) * 8);
            #pragma unroll
            for (int mi = 0; mi < 2; ++mi)
                #pragma unroll
                for (int ni = 0; ni < 4; ++ni)
                    acc[mi][ni] = __builtin_amdgcn_mfma_f32_16x16x32_bf16(
                        af[mi], bfv[ni], acc[mi][ni], 0, 0, 0);
        }
        __syncthreads();                        // next tile staged + reads done
        cur ^= 1;
    }

    // ---- epilogue ----
    float nb[4]; int gl[4];
    #pragma unroll
    for (int ni = 0; ni < 4; ++ni) {
        int col = n0 + wc + ni*16 + lc;
        nb[ni] = normL[col];
        gl[ni] = label_batch[col];
    }
    float na[8]; int gr[8];
    #pragma unroll
    for (int mi = 0; mi < 2; ++mi)
        #pragma unroll
        for (int r = 0; r < 4; ++r) {
            int row = m0 + wr + mi*16 + quad*4 + r;
            na[mi*4 + r] = normN[row];
            gr[mi*4 + r] = node_batch[row];
        }

    // dot -> clamped squared distance (in place); sqrt deferred to finalize
    #pragma unroll
    for (int mi = 0; mi < 2; ++mi)
        #pragma unroll
        for (int ni = 0; ni < 4; ++ni)
            #pragma unroll
            for (int r = 0; r < 4; ++r)
                acc[mi][ni][r] = fmaxf(
                    fmaf(-2.0f, acc[mi][ni][r], na[mi*4 + r] + nb[ni]), 0.0f);

    const float FINF = __uint_as_float(INF_BITS);

    // ---- per-row min over columns, grouped by label graph ----
    // wave col window = [n0+wc, n0+wc+63] (sorted by label_batch)
    int glo = label_batch[n0 + wc], ghi = label_batch[n0 + wc + 63];
    if (glo == ghi) {
        // fast path: single label graph -> unsegmented min over 64 cols
        float rm[8];
        #pragma unroll
        for (int mi = 0; mi < 2; ++mi)
            #pragma unroll
            for (int r = 0; r < 4; ++r) {
                float m = fminf(fminf(acc[mi][0][r], acc[mi][1][r]),
                                fminf(acc[mi][2][r], acc[mi][3][r]));
                m = fminf(m, __shfl_xor(m, 1, 64));
                m = fminf(m, __shfl_xor(m, 2, 64));
                m = fminf(m, __shfl_xor(m, 4, 64));
                m = fminf(m, __shfl_xor(m, 8, 64));
                rm[mi*4 + r] = m;
            }
        if (lc == 0) {
            #pragma unroll
            for (int mi = 0; mi < 2; ++mi)
                #pragma unroll
                for (int r = 0; r < 4; ++r) {
                    int row = m0 + wr + mi*16 + quad*4 + r;
                    atomicMin(&bufN[row * NG + glo], __float_as_uint(rm[mi*4 + r]));
                }
        }
    } else {
        for (int g = glo; g <= ghi; ++g) {
            bool s0 = (gl[0] == g), s1 = (gl[1] == g), s2 = (gl[2] == g), s3 = (gl[3] == g);
            float rm[8];
            #pragma unroll
            for (int mi = 0; mi < 2; ++mi)
                #pragma unroll
                for (int r = 0; r < 4; ++r) {
                    float m = s0 ? acc[mi][0][r] : FINF;
                    m = fminf(m, s1 ? acc[mi][1][r] : FINF);
                    m = fminf(m, s2 ? acc[mi][2][r] : FINF);
                    m = fminf(m, s3 ? acc[mi][3][r] : FINF);
                    m = fminf(m, __shfl_xor(m, 1, 64));
                    m = fminf(m, __shfl_xor(m, 2, 64));
                    m = fminf(m, __shfl_xor(m, 4, 64));
                    m = fminf(m, __shfl_xor(m, 8, 64));
                    rm[mi*4 + r] = m;
                }
            if (lc == 0) {
                #pragma unroll
                for (int mi = 0; mi < 2; ++mi)
                    #pragma unroll
                    for (int r = 0; r < 4; ++r) {
                        int row = m0 + wr + mi*16 + quad*4 + r;
                        atomicMin(&bufN[row * NG + g], __float_as_uint(rm[mi*4 + r]));
                    }
            }
        }
    }

    // ---- per-col min over rows, grouped by node graph ----
    // wave row window = [m0+wr, m0+wr+31] (sorted by node_batch)
    int rlo = node_batch[m0 + wr], rhi = node_batch[m0 + wr + 31];
    if (rlo == rhi) {
        // fast path: single node graph -> unsegmented min over 32 rows
        float cm[4];
        #pragma unroll
        for (int ni = 0; ni < 4; ++ni) {
            float m = acc[0][ni][0];
            m = fminf(m, acc[0][ni][1]); m = fminf(m, acc[0][ni][2]);
            m = fminf(m, acc[0][ni][3]); m = fminf(m, acc[1][ni][0]);
            m = fminf(m, acc[1][ni][1]); m = fminf(m, acc[1][ni][2]);
            m = fminf(m, acc[1][ni][3]);
            m = fminf(m, __shfl_xor(m, 16, 64));
            m = fminf(m, __shfl_xor(m, 32, 64));
            cm[ni] = m;
        }
        if (quad == 0) {
            #pragma unroll
            for (int ni = 0; ni < 4; ++ni) {
                int col = n0 + wc + ni*16 + lc;
                atomicMin(&bufL[rlo * EL + col], __float_as_uint(cm[ni]));
            }
        }
    } else {
        for (int g = rlo; g <= rhi; ++g) {
            float cm[4];
            #pragma unroll
            for (int ni = 0; ni < 4; ++ni) {
                float m = FINF;
                #pragma unroll
                for (int mi = 0; mi < 2; ++mi)
                    #pragma unroll
                    for (int r = 0; r < 4; ++r)
                        m = fminf(m, (gr[mi*4 + r] == g) ? acc[mi][ni][r] : FINF);
                m = fminf(m, __shfl_xor(m, 16, 64));
                m = fminf(m, __shfl_xor(m, 32, 64));
                cm[ni] = m;
            }
            if (quad == 0) {
                #pragma unroll
                for (int ni = 0; ni < 4; ++ni) {
                    int col = n0 + wc + ni*16 + lc;
                    atomicMin(&bufL[g * EL + col], __float_as_uint(cm[ni]));
                }
            }
        }
    }
}

// ---------------- kernel 3: segment means + combine ----------------
__device__ __forceinline__ int lbound(const int* __restrict__ a, int n, int v) {
    int lo = 0, hi = n;
    while (lo < hi) { int mid = (lo + hi) >> 1; if (a[mid] < v) lo = mid + 1; else hi = mid; }
    return lo;
}

// one block per node-graph gn; MUST be launched with 1024 threads
__global__ void finalize(const unsigned* __restrict__ bufN,
                         const unsigned* __restrict__ bufL,
                         const int* __restrict__ node_batch,
                         const int* __restrict__ label_batch,
                         float* __restrict__ out)
{
    __shared__ float sN[NG];   // sum over rows of -dist, per label graph
    __shared__ float sL[NG];   // sum over cols of -dist, per label graph
    int gn  = blockIdx.x;
    int tid = threadIdx.x;
    if (tid < NG) { sN[tid] = 0.0f; sL[tid] = 0.0f; }
    __syncthreads();

    int ns = lbound(node_batch, EN, gn);
    int ne = lbound(node_batch, EN, gn + 1);

    // part 1: bufN slice [ns:ne) x NG -> per-label sums (coalesced across t)
    {
        int t = tid & 63, strip = tid >> 6;          // 16 row strips
        float acc = 0.0f;
        for (int i = ns + strip; i < ne; i += 16) {
            unsigned b = bufN[i * NG + t];
            if (b != INF_BITS) acc -= sqrtf(__uint_as_float(b));
        }
        atomicAdd(&sN[t], acc);
    }

    // part 2: bufL row gn (8192 cols, coalesced), scatter by label graph
    for (int j = tid; j < EL; j += 1024) {
        unsigned b = bufL[gn * EL + j];
        if (b != INF_BITS) {
            int g = label_batch[j];
            atomicAdd(&sL[g], -sqrtf(__uint_as_float(b)));
        }
    }
    __syncthreads();

    if (tid < NG) {
        int t = tid;
        int cn = ne - ns;
        int ls = lbound(label_batch, EL, t);
        int le = lbound(label_batch, EL, t + 1);
        int cl = le - ls;
        float out_n = sN[t] / (float)(cn > 0 ? cn : 1);
        float out_l = sL[t] / (float)(cl > 0 ? cl : 1);
        out[gn * NG + t] = 0.5f * (out_n + out_l);
    }
}

extern "C" void kernel_launch(void* const* d_in, const int* in_sizes, int n_in,
                              void* d_out, int out_size, void* d_ws, size_t ws_size,
                              hipStream_t stream)
{
    const float* h          = (const float*)d_in[0];
    const int* node_edge    = (const int*)d_in[1];
    const int* node_batch   = (const int*)d_in[2];
    const int* label_edge   = (const int*)d_in[3];
    const int* label_batch  = (const int*)d_in[4];
    float* out = (float*)d_out;

    char* ws = (char*)d_ws;
    unsigned short* efn = (unsigned short*)ws; ws += (size_t)EN * D * 2;
    unsigned short* efl = (unsigned short*)ws; ws += (size_t)EL * D * 2;
    float* normN = (float*)ws;                 ws += (size_t)EN * 4;
    float* normL = (float*)ws;                 ws += (size_t)EL * 4;
    unsigned* bufN = (unsigned*)ws;            ws += (size_t)EN * NG * 4;
    unsigned* bufL = (unsigned*)ws;            ws += (size_t)NG * EL * 4;

    // bufN,bufL contiguous: 1024 init blocks + 2048 + 2048 edge blocks
    prep<<<5120, 256, 0, stream>>>(h, node_edge, label_edge,
                                   efn, normN, efl, normL, bufN);
    dist_min<<<dim3(EL / 128, EN / 128), 512, 0, stream>>>(
        efn, efl, normN, normL, node_batch, label_batch, bufN, bufL);
    finalize<<<NG, 1024, 0, stream>>>(bufN, bufL, node_batch, label_batch, out);
}

// Round 3
// 188.318 us; speedup vs baseline: 1.0196x; 1.0196x over previous
//
#include <hip/hip_runtime.h>
#include <hip/hip_bf16.h>
#include <math.h>

#define EN 8192
#define EL 8192
#define D  256
#define NG 64
#define QTILES 8            // B col-tiles per block (1024 cols per block)
#define INF_BITS 0x7f800000u

typedef __attribute__((ext_vector_type(8))) short  bf16x8;
typedef __attribute__((ext_vector_type(4))) float  f32x4;

__device__ __forceinline__ unsigned short f2bf(float f) {
    unsigned u = __float_as_uint(f);
    unsigned r = (u + 0x7fffu + ((u >> 16) & 1u)) >> 16;   // RNE
    return (unsigned short)r;
}

// ---------------- kernel 1: fused init + edge features ----------------
// blocks [0,1024): fill bufN/bufL (contiguous 4 MB) with +inf via uint4
// blocks [1024,3072): edge features for node set
// blocks [3072,5120): edge features for label set
__global__ void prep(const float* __restrict__ h,
                     const int* __restrict__ node_edge,
                     const int* __restrict__ label_edge,
                     unsigned short* __restrict__ efn, float* __restrict__ normN,
                     unsigned short* __restrict__ efl, float* __restrict__ normL,
                     unsigned* __restrict__ inf_buf)
{
    int b = blockIdx.x;
    if (b < 1024) {
        uint4 v = make_uint4(INF_BITS, INF_BITS, INF_BITS, INF_BITS);
        ((uint4*)inf_buf)[b * 256 + threadIdx.x] = v;
        return;
    }
    b -= 1024;
    const int* edges; unsigned short* ef; float* norm;
    if (b < 2048) { edges = node_edge;  ef = efn; norm = normN; }
    else          { b -= 2048; edges = label_edge; ef = efl; norm = normL; }

    int wave = threadIdx.x >> 6;
    int lane = threadIdx.x & 63;
    int e = b * 4 + wave;
    int a  = edges[e];
    int bb = edges[EN + e];          // En == El == 8192
    float4 va = ((const float4*)(h + (size_t)a  * D))[lane];
    float4 vb = ((const float4*)(h + (size_t)bb * D))[lane];
    float4 f;
    f.x = 0.5f * (va.x + vb.x);
    f.y = 0.5f * (va.y + vb.y);
    f.z = 0.5f * (va.z + vb.z);
    f.w = 0.5f * (va.w + vb.w);
    float sq = f.x*f.x + f.y*f.y + f.z*f.z + f.w*f.w;
    ushort4 pk;
    pk.x = f2bf(f.x); pk.y = f2bf(f.y); pk.z = f2bf(f.z); pk.w = f2bf(f.w);
    ((ushort4*)(ef + (size_t)e * D))[lane] = pk;
    #pragma unroll
    for (int off = 1; off < 64; off <<= 1)
        sq += __shfl_xor(sq, off, 64);
    if (lane == 0) norm[e] = sq;
}

// ---------------- kernel 2: fused GEMM + sq-distance + segmented min ----------------
// R2 restructure (K=256 is short: 4 K-steps): A panel is LDS-RESIDENT.
// Each block = (row-panel m0 of 128 rows, col-chunk q of 1024 cols):
//   - stage full-K A panel once (64 KB), then sweep 8 B col-tiles,
//     double-buffering B in BK=128 chunks (2 x 32 KB). Total LDS 128 KB,
//     1 block/CU, 8 waves.
//   - per tile-pair: 2 barriers (was 5) and zero A re-staging; B prefetch
//     is issued one full chunk (~2.3K cyc of compute) ahead, so L2/LLC
//     latency hides under MFMA+ds_read of the current chunk.
//   - epilogue (unchanged math, verified prior session) runs barrier-free
//     after the 2nd chunk barrier; the next tile's first chunk is already
//     staged, so epilogue time doesn't stall the pipeline.
// XOR-swizzle: phys k-chunk = logical ^ (row&7) (low-3-bit involution) on
// both stage-source and ds_read -> 2 lanes/bank pair = free (m136).
// Default linear->XCD round robin puts q = blockIdx.x on one XCD: per-XCD
// working set = A (4 MB, all panels) + B strip (512 KB) ~ L2-resident.
__launch_bounds__(512, 2)
__global__ void dist_min(const unsigned short* __restrict__ A,   // ef_n [EN][D]
                         const unsigned short* __restrict__ B,   // ef_l [EL][D]
                         const float* __restrict__ normN,
                         const float* __restrict__ normL,
                         const int* __restrict__ node_batch,
                         const int* __restrict__ label_batch,
                         unsigned* __restrict__ bufN,  // [EN][NG] min sq-dist bits
                         unsigned* __restrict__ bufL)  // [NG][EL] min sq-dist bits
{
    __shared__ unsigned short As[128 * 256];      // 64 KB: full-K A panel
    __shared__ unsigned short Bs[2][128 * 128];   // 2 x 32 KB: BK=128 B chunks

    const int tid  = threadIdx.x;
    const int lane = tid & 63;
    const int wave = tid >> 6;          // 0..7
    const int quad = lane >> 4;
    const int lc   = lane & 15;
    const int m0   = blockIdx.y * 128;
    const int q    = blockIdx.x;        // 0..7 -> cols [q*1024, q*1024+1024)
    const int wr   = (wave >> 1) * 32;  // 4 row groups of 32
    const int wc   = (wave & 1) * 64;   // 2 col groups of 64

    // ---- stage full-K A panel once: 4096 chunks of 16 B ----
    // phys chunk (row, cc) holds global chunk (row, cc ^ (row&7))
    #pragma unroll
    for (int t = 0; t < 8; ++t) {
        int c = t * 512 + tid;              // 0..4095
        int row = c >> 5, cc = c & 31;
        int scc = cc ^ (row & 7);           // low-3 XOR, stays in [0,32)
        const unsigned short* gp = A + (size_t)(m0 + row) * D + scc * 8;
        __builtin_amdgcn_global_load_lds(
            (const __attribute__((address_space(1))) void*)gp,
            (__attribute__((address_space(3))) void*)(As + c * 8), 16, 0, 0);
    }

    // stage one BK=128 chunk (ck of 2) of B col-tile ot into Bs[buf]
    auto stageB = [&](int buf, int ot, int ck) {
        int n0t = q * (QTILES * 128) + ot * 128;
        #pragma unroll
        for (int t = 0; t < 4; ++t) {
            int c = t * 512 + tid;          // 0..2047
            int row = c >> 4, cc = c & 15;
            int scc = cc ^ (row & 7);       // low-3 XOR, stays in [0,16)
            const unsigned short* gp =
                B + (size_t)(n0t + row) * D + ck * 128 + scc * 8;
            __builtin_amdgcn_global_load_lds(
                (const __attribute__((address_space(1))) void*)gp,
                (__attribute__((address_space(3))) void*)(Bs[buf] + c * 8), 16, 0, 0);
        }
    };

    stageB(0, 0, 0);

    // hoisted row-side epilogue data (row panel fixed per block); these
    // gathers overlap the prologue staging latency
    float na[8]; int gr[8];
    #pragma unroll
    for (int mi = 0; mi < 2; ++mi)
        #pragma unroll
        for (int r = 0; r < 4; ++r) {
            int row = m0 + wr + mi*16 + quad*4 + r;
            na[mi*4 + r] = normN[row];
            gr[mi*4 + r] = node_batch[row];
        }
    const int rlo = node_batch[m0 + wr], rhi = node_batch[m0 + wr + 31];
    const float FINF = __uint_as_float(INF_BITS);

    __syncthreads();                        // prologue staged

    int buf = 0;
    for (int ot = 0; ot < QTILES; ++ot) {
        const int n0t = q * (QTILES * 128) + ot * 128;

        // per-tile col-side epilogue data: issue loads early, consume after
        // the two compute chunks (latency hidden under ~4.6K cyc of compute)
        float nb[4]; int gl[4];
        #pragma unroll
        for (int ni = 0; ni < 4; ++ni) {
            int col = n0t + wc + ni*16 + lc;
            nb[ni] = normL[col];
            gl[ni] = label_batch[col];
        }
        int glo = label_batch[n0t + wc], ghi = label_batch[n0t + wc + 63];

        f32x4 acc[2][4];
        #pragma unroll
        for (int i = 0; i < 2; ++i)
            #pragma unroll
            for (int j = 0; j < 4; ++j) {
                f32x4 z = {0.f, 0.f, 0.f, 0.f};
                acc[i][j] = z;
            }

        #pragma unroll
        for (int ck = 0; ck < 2; ++ck) {
            // prefetch next chunk into the other buffer (safe: every wave's
            // reads of that buffer completed before the previous barrier)
            if (!(ot == QTILES - 1 && ck == 1))
                stageB(buf ^ 1, ck ? ot + 1 : ot, ck ^ 1);

            #pragma unroll
            for (int kt2 = 0; kt2 < 2; ++kt2) {
                #pragma unroll
                for (int kk = 0; kk < 2; ++kk) {
                    bf16x8 af[2], bfv[4];
                    int kg = (ck*2 + kt2)*8 + kk*4 + quad;   // A k-chunk 0..31
                    int kb = kt2*8 + kk*4 + quad;            // B k-chunk 0..15
                    #pragma unroll
                    for (int mi = 0; mi < 2; ++mi)
                        af[mi] = *(const bf16x8*)(As + (wr + mi*16 + lc) * 256
                                                     + (kg ^ (lc & 7)) * 8);
                    #pragma unroll
                    for (int ni = 0; ni < 4; ++ni)
                        bfv[ni] = *(const bf16x8*)(Bs[buf] + (wc + ni*16 + lc) * 128
                                                      + (kb ^ (lc & 7)) * 8);
                    #pragma unroll
                    for (int mi = 0; mi < 2; ++mi)
                        #pragma unroll
                        for (int ni = 0; ni < 4; ++ni)
                            acc[mi][ni] = __builtin_amdgcn_mfma_f32_16x16x32_bf16(
                                af[mi], bfv[ni], acc[mi][ni], 0, 0, 0);
                }
            }
            __syncthreads();                // next chunk staged + reads done
            buf ^= 1;
        }

        // ---- epilogue for col-tile ot (no LDS, no barriers) ----
        // dot -> clamped squared distance (in place); sqrt deferred
        #pragma unroll
        for (int mi = 0; mi < 2; ++mi)
            #pragma unroll
            for (int ni = 0; ni < 4; ++ni)
                #pragma unroll
                for (int r = 0; r < 4; ++r)
                    acc[mi][ni][r] = fmaxf(
                        fmaf(-2.0f, acc[mi][ni][r], na[mi*4 + r] + nb[ni]), 0.0f);

        // per-row min over columns, grouped by label graph
        if (glo == ghi) {
            float rm[8];
            #pragma unroll
            for (int mi = 0; mi < 2; ++mi)
                #pragma unroll
                for (int r = 0; r < 4; ++r) {
                    float m = fminf(fminf(acc[mi][0][r], acc[mi][1][r]),
                                    fminf(acc[mi][2][r], acc[mi][3][r]));
                    m = fminf(m, __shfl_xor(m, 1, 64));
                    m = fminf(m, __shfl_xor(m, 2, 64));
                    m = fminf(m, __shfl_xor(m, 4, 64));
                    m = fminf(m, __shfl_xor(m, 8, 64));
                    rm[mi*4 + r] = m;
                }
            if (lc == 0) {
                #pragma unroll
                for (int mi = 0; mi < 2; ++mi)
                    #pragma unroll
                    for (int r = 0; r < 4; ++r) {
                        int row = m0 + wr + mi*16 + quad*4 + r;
                        atomicMin(&bufN[row * NG + glo], __float_as_uint(rm[mi*4 + r]));
                    }
            }
        } else {
            for (int g = glo; g <= ghi; ++g) {
                bool s0 = (gl[0] == g), s1 = (gl[1] == g),
                     s2 = (gl[2] == g), s3 = (gl[3] == g);
                float rm[8];
                #pragma unroll
                for (int mi = 0; mi < 2; ++mi)
                    #pragma unroll
                    for (int r = 0; r < 4; ++r) {
                        float m = s0 ? acc[mi][0][r] : FINF;
                        m = fminf(m, s1 ? acc[mi][1][r] : FINF);
                        m = fminf(m, s2 ? acc[mi][2][r] : FINF);
                        m = fminf(m, s3 ? acc[mi][3][r] : FINF);
                        m = fminf(m, __shfl_xor(m, 1, 64));
                        m = fminf(m, __shfl_xor(m, 2, 64));
                        m = fminf(m, __shfl_xor(m, 4, 64));
                        m = fminf(m, __shfl_xor(m, 8, 64));
                        rm[mi*4 + r] = m;
                    }
                if (lc == 0) {
                    #pragma unroll
                    for (int mi = 0; mi < 2; ++mi)
                        #pragma unroll
                        for (int r = 0; r < 4; ++r) {
                            int row = m0 + wr + mi*16 + quad*4 + r;
                            atomicMin(&bufN[row * NG + g], __float_as_uint(rm[mi*4 + r]));
                        }
                }
            }
        }

        // per-col min over rows, grouped by node graph
        if (rlo == rhi) {
            float cm[4];
            #pragma unroll
            for (int ni = 0; ni < 4; ++ni) {
                float m = acc[0][ni][0];
                m = fminf(m, acc[0][ni][1]); m = fminf(m, acc[0][ni][2]);
                m = fminf(m, acc[0][ni][3]); m = fminf(m, acc[1][ni][0]);
                m = fminf(m, acc[1][ni][1]); m = fminf(m, acc[1][ni][2]);
                m = fminf(m, acc[1][ni][3]);
                m = fminf(m, __shfl_xor(m, 16, 64));
                m = fminf(m, __shfl_xor(m, 32, 64));
                cm[ni] = m;
            }
            if (quad == 0) {
                #pragma unroll
                for (int ni = 0; ni < 4; ++ni) {
                    int col = n0t + wc + ni*16 + lc;
                    atomicMin(&bufL[rlo * EL + col], __float_as_uint(cm[ni]));
                }
            }
        } else {
            for (int g = rlo; g <= rhi; ++g) {
                float cm[4];
                #pragma unroll
                for (int ni = 0; ni < 4; ++ni) {
                    float m = FINF;
                    #pragma unroll
                    for (int mi = 0; mi < 2; ++mi)
                        #pragma unroll
                        for (int r = 0; r < 4; ++r)
                            m = fminf(m, (gr[mi*4 + r] == g) ? acc[mi][ni][r] : FINF);
                    m = fminf(m, __shfl_xor(m, 16, 64));
                    m = fminf(m, __shfl_xor(m, 32, 64));
                    cm[ni] = m;
                }
                if (quad == 0) {
                    #pragma unroll
                    for (int ni = 0; ni < 4; ++ni) {
                        int col = n0t + wc + ni*16 + lc;
                        atomicMin(&bufL[g * EL + col], __float_as_uint(cm[ni]));
                    }
                }
            }
        }
    }
}

// ---------------- kernel 3: segment means + combine ----------------
__device__ __forceinline__ int lbound(const int* __restrict__ a, int n, int v) {
    int lo = 0, hi = n;
    while (lo < hi) { int mid = (lo + hi) >> 1; if (a[mid] < v) lo = mid + 1; else hi = mid; }
    return lo;
}

// one block per node-graph gn; MUST be launched with 1024 threads
__global__ void finalize(const unsigned* __restrict__ bufN,
                         const unsigned* __restrict__ bufL,
                         const int* __restrict__ node_batch,
                         const int* __restrict__ label_batch,
                         float* __restrict__ out)
{
    __shared__ float sN[NG];   // sum over rows of -dist, per label graph
    __shared__ float sL[NG];   // sum over cols of -dist, per label graph
    int gn  = blockIdx.x;
    int tid = threadIdx.x;
    if (tid < NG) { sN[tid] = 0.0f; sL[tid] = 0.0f; }
    __syncthreads();

    int ns = lbound(node_batch, EN, gn);
    int ne = lbound(node_batch, EN, gn + 1);

    // part 1: bufN slice [ns:ne) x NG -> per-label sums (coalesced across t)
    {
        int t = tid & 63, strip = tid >> 6;          // 16 row strips
        float acc = 0.0f;
        for (int i = ns + strip; i < ne; i += 16) {
            unsigned b = bufN[i * NG + t];
            if (b != INF_BITS) acc -= sqrtf(__uint_as_float(b));
        }
        atomicAdd(&sN[t], acc);
    }

    // part 2: bufL row gn (8192 cols, coalesced), scatter by label graph
    for (int j = tid; j < EL; j += 1024) {
        unsigned b = bufL[gn * EL + j];
        if (b != INF_BITS) {
            int g = label_batch[j];
            atomicAdd(&sL[g], -sqrtf(__uint_as_float(b)));
        }
    }
    __syncthreads();

    if (tid < NG) {
        int t = tid;
        int cn = ne - ns;
        int ls = lbound(label_batch, EL, t);
        int le = lbound(label_batch, EL, t + 1);
        int cl = le - ls;
        float out_n = sN[t] / (float)(cn > 0 ? cn : 1);
        float out_l = sL[t] / (float)(cl > 0 ? cl : 1);
        out[gn * NG + t] = 0.5f * (out_n + out_l);
    }
}

extern "C" void kernel_launch(void* const* d_in, const int* in_sizes, int n_in,
                              void* d_out, int out_size, void* d_ws, size_t ws_size,
                              hipStream_t stream)
{
    const float* h          = (const float*)d_in[0];
    const int* node_edge    = (const int*)d_in[1];
    const int* node_batch   = (const int*)d_in[2];
    const int* label_edge   = (const int*)d_in[3];
    const int* label_batch  = (const int*)d_in[4];
    float* out = (float*)d_out;

    char* ws = (char*)d_ws;
    unsigned short* efn = (unsigned short*)ws; ws += (size_t)EN * D * 2;
    unsigned short* efl = (unsigned short*)ws; ws += (size_t)EL * D * 2;
    float* normN = (float*)ws;                 ws += (size_t)EN * 4;
    float* normL = (float*)ws;                 ws += (size_t)EL * 4;
    unsigned* bufN = (unsigned*)ws;            ws += (size_t)EN * NG * 4;
    unsigned* bufL = (unsigned*)ws;            ws += (size_t)NG * EL * 4;

    // bufN,bufL contiguous: 1024 init blocks + 2048 + 2048 edge blocks
    prep<<<5120, 256, 0, stream>>>(h, node_edge, label_edge,
                                   efn, normN, efl, normL, bufN);
    dist_min<<<dim3(QTILES, EN / 128), 512, 0, stream>>>(
        efn, efl, normN, normL, node_batch, label_batch, bufN, bufL);
    finalize<<<NG, 1024, 0, stream>>>(bufN, bufL, node_batch, label_batch, out);
}